// Round 9
// baseline (66.465 us; speedup 1.0000x reference)
//
#include <hip/hip_runtime.h>

// FeatureLayer: out[row] = concat( sum_k W_item[item_hist[row,k]],        (64)
//                                  mean_k W_cate[cate_hist[row,k]],       (64)
//                                  concat_k W_ctx[ctx_ids[row,k]],        (640)
//                                  price[row],                            (1)
//                                  dense_vec[row] )                       (128)
// padding_idx = 0: index 0 contributes zeros. Mean divides by L=50 incl. padding.
//
// R8 model: gather cost = L2-line misses (128 B fill granule; fp16 row = 1
// line = floor). int8 didn't cut FETCH (R7) -> revert to fp16 gathers.
// Lever: raise L2 hit rate on gather lines by keeping the 74 MB of
// streaming traffic out of L2: NT stores on block-contiguous output,
// NT loads on read-once streams. + fp16 ctx table (64 KB, L2-resident).

#define LH 50
#define LC 20
#define DI 64
#define DC 64
#define DX 32
#define DDENSE 128
#define OUT_D 897
#define ROWS 4
#define BLK_OUT (ROWS * OUT_D)   // 3588 floats = 897 float4 exactly
#define NROW_TAB 100000
#define TAB_ELEMS (NROW_TAB * 64)
#define NIT8 7     // ceil(LH/8)
#define CTX_CHUNKS 8000          // 1000*32/4 f32x4 chunks

typedef float    f32x4 __attribute__((ext_vector_type(4)));
typedef _Float16 f16x4 __attribute__((ext_vector_type(4)));
typedef _Float16 f16x8 __attribute__((ext_vector_type(8)));

// ---------------- pre-pass: fp32 tables + ctx -> fp16 in workspace ----------------
__global__ __launch_bounds__(256) void convert_kernel(
    const float* __restrict__ Wi, const float* __restrict__ Wc,
    const float* __restrict__ Wx,
    _Float16* __restrict__ Hi, _Float16* __restrict__ Hc,
    _Float16* __restrict__ Hx)
{
    const int gid    = blockIdx.x * 256 + threadIdx.x;
    const int stride = gridDim.x * 256;
    for (int i = gid; i < TAB_ELEMS / 4; i += stride) {
        const f32x4 a = __builtin_nontemporal_load(
            reinterpret_cast<const f32x4*>(Wi) + i);
        const f32x4 b = __builtin_nontemporal_load(
            reinterpret_cast<const f32x4*>(Wc) + i);
        f16x4 ha, hb;
        #pragma unroll
        for (int e = 0; e < 4; ++e) { ha[e] = (_Float16)a[e]; hb[e] = (_Float16)b[e]; }
        reinterpret_cast<f16x4*>(Hi)[i] = ha;   // normal store: want L2/L3 warm
        reinterpret_cast<f16x4*>(Hc)[i] = hb;
    }
    if (gid < CTX_CHUNKS) {
        const f32x4 v = reinterpret_cast<const f32x4*>(Wx)[gid];
        f16x4 h;
        #pragma unroll
        for (int e = 0; e < 4; ++e) h[e] = (_Float16)v[e];
        reinterpret_cast<f16x4*>(Hx)[gid] = h;
    }
}

// ---------------- main kernel ----------------
template <bool HALF>
__global__ __launch_bounds__(256) void featlayer_kernel(
    const int* __restrict__ item_hist,
    const int* __restrict__ cate_hist,
    const int* __restrict__ ctx_ids,
    const float* __restrict__ price,
    const float* __restrict__ dense_vec,
    const float* __restrict__ W_item,
    const float* __restrict__ W_cate,
    const _Float16* __restrict__ H_item,
    const _Float16* __restrict__ H_cate,
    const _Float16* __restrict__ Hx,
    const float* __restrict__ W_ctx,
    float* __restrict__ out,
    int B)
{
    __shared__ __align__(16) float obuf[BLK_OUT];
    __shared__ int ih_s[ROWS * LH];
    __shared__ int ch_s[ROWS * LH];
    __shared__ int cx_s[ROWS * LC];

    const int t     = threadIdx.x;
    const int rbase = blockIdx.x * ROWS;

    // ---- stage indices (read-once streams: NT) ----
    if (t < ROWS * LH) {
        ih_s[t] = __builtin_nontemporal_load(item_hist + (size_t)rbase * LH + t);
        ch_s[t] = __builtin_nontemporal_load(cate_hist + (size_t)rbase * LH + t);
    }
    if (t < ROWS * LC)
        cx_s[t] = __builtin_nontemporal_load(ctx_ids + (size_t)rbase * LC + t);

    // ---- dense: 512 floats = 128 float4, threads 0..127 (NT read-once) ----
    if (t < 128) {
        const int r = t >> 5;
        const int c = t & 31;
        const f32x4 dvv = __builtin_nontemporal_load(
            reinterpret_cast<const f32x4*>(
                dense_vec + ((size_t)(rbase + r) * DDENSE)) + c);
        float* o = obuf + r * OUT_D + (DI + DC + LC * DX + 1) + c * 4;
        o[0] = dvv.x; o[1] = dvv.y; o[2] = dvv.z; o[3] = dvv.w;
    }
    if (t < ROWS)
        obuf[t * OUT_D + DI + DC + LC * DX] =
            __builtin_nontemporal_load(price + rbase + t);

    __syncthreads();

    const int w    = t >> 6;
    const int lane = t & 63;

    if (HALF) {
        // 8 lanes per table row (f16x8 = 16B per lane): one row = one L2 line
        const int sub8 = lane >> 3;   // 0..7: which index within a group of 8
        const int l8   = lane & 7;    // 0..7: which f16x8 of the 64-dim row

        int idxI[NIT8], idxC[NIT8];
        #pragma unroll
        for (int k = 0; k < NIT8; ++k) {
            const int ki = sub8 + 8 * k;
            idxI[k] = (ki < LH) ? ih_s[w * LH + ki] : 0;
            idxC[k] = (ki < LH) ? ch_s[w * LH + ki] : 0;
        }

        float iacc[8] = {0,0,0,0,0,0,0,0};
        float cacc[8] = {0,0,0,0,0,0,0,0};
        #pragma unroll
        for (int k = 0; k < NIT8; ++k) {
            const f16x8 vi = *reinterpret_cast<const f16x8*>(
                H_item + ((size_t)idxI[k] * 64 + l8 * 8));
            const f16x8 vc = *reinterpret_cast<const f16x8*>(
                H_cate + ((size_t)idxC[k] * 64 + l8 * 8));
            const float si = (idxI[k] != 0) ? 1.0f : 0.0f;  // padding_idx
            const float sc = (idxC[k] != 0) ? 1.0f : 0.0f;
            #pragma unroll
            for (int e = 0; e < 8; ++e) {
                iacc[e] += (float)vi[e] * si;
                cacc[e] += (float)vc[e] * sc;
            }
        }

        // combine 8 sub-group partials (lanes l, l+8, ..., l+56)
        #pragma unroll
        for (int e = 0; e < 8; ++e) {
            float a = iacc[e];
            a += __shfl_xor(a, 8, 64);
            a += __shfl_xor(a, 16, 64);
            a += __shfl_xor(a, 32, 64);
            iacc[e] = a;
            float c = cacc[e];
            c += __shfl_xor(c, 8, 64);
            c += __shfl_xor(c, 16, 64);
            c += __shfl_xor(c, 32, 64);
            cacc[e] = c;
        }

        if (sub8 == 0) {   // lanes 0..7, lane l8 owns dims [l8*8, l8*8+8)
            float* oi = obuf + w * OUT_D + l8 * 8;
            float* oc = obuf + w * OUT_D + DI + l8 * 8;
            const float inv = 1.0f / (float)LH;
            #pragma unroll
            for (int e = 0; e < 8; ++e) {
                oi[e] = iacc[e];
                oc[e] = cacc[e] * inv;
            }
        }

        // ---- ctx via fp16 table (64 KB, L2-resident): 80 f16x8 chunks/row ----
        #pragma unroll
        for (int t2 = 0; t2 < 2; ++t2) {
            const int c = lane + 64 * t2;
            if (c < (LC * DX) / 8) {               // 80 chunks of 8
                const int id = cx_s[w * LC + (c >> 2)];  // 4 chunks per ctx id
                float* o = obuf + w * OUT_D + DI + DC + 8 * c;
                if (id != 0) {
                    const f16x8 v = *reinterpret_cast<const f16x8*>(
                        Hx + ((size_t)id * DX + (c & 3) * 8));
                    #pragma unroll
                    for (int e = 0; e < 8; ++e) o[e] = (float)v[e];
                } else {
                    #pragma unroll
                    for (int e = 0; e < 8; ++e) o[e] = 0.0f;
                }
            }
        }
    } else {
        // fp32 fallback: 16 lanes per row (f32x4 per lane)
        const int sub = lane >> 4;
        const int l16 = lane & 15;
        int idxI[13], idxC[13];
        #pragma unroll
        for (int k = 0; k < 13; ++k) {
            const int ki = sub + 4 * k;
            idxI[k] = (ki < LH) ? ih_s[w * LH + ki] : 0;
            idxC[k] = (ki < LH) ? ch_s[w * LH + ki] : 0;
        }
        f32x4 iacc = {0,0,0,0}, cacc = {0,0,0,0};
        #pragma unroll
        for (int k = 0; k < 13; ++k) {
            const f32x4 vi = *reinterpret_cast<const f32x4*>(
                W_item + ((size_t)idxI[k] * DI + l16 * 4));
            const f32x4 vc = *reinterpret_cast<const f32x4*>(
                W_cate + ((size_t)idxC[k] * DC + l16 * 4));
            iacc += vi * ((idxI[k] != 0) ? 1.0f : 0.0f);
            cacc += vc * ((idxC[k] != 0) ? 1.0f : 0.0f);
        }
        #pragma unroll
        for (int e = 0; e < 4; ++e) {
            float a = iacc[e];
            a += __shfl_xor(a, 16, 64); a += __shfl_xor(a, 32, 64);
            iacc[e] = a;
            float c = cacc[e];
            c += __shfl_xor(c, 16, 64); c += __shfl_xor(c, 32, 64);
            cacc[e] = c;
        }
        if (sub == 0) {
            float* oi = obuf + w * OUT_D + l16 * 4;
            float* oc = obuf + w * OUT_D + DI + l16 * 4;
            const float inv = 1.0f / (float)LH;
            #pragma unroll
            for (int e = 0; e < 4; ++e) { oi[e] = iacc[e]; oc[e] = cacc[e] * inv; }
        }
        #pragma unroll
        for (int t2 = 0; t2 < 3; ++t2) {
            const int c = lane + 64 * t2;
            if (c < (LC * DX) / 4) {
                const int id = cx_s[w * LC + (c >> 3)];
                f32x4 v = {0.f, 0.f, 0.f, 0.f};
                if (id != 0)
                    v = *reinterpret_cast<const f32x4*>(
                        W_ctx + ((size_t)id * DX + (c & 7) * 4));
                float* o = obuf + w * OUT_D + DI + DC + 4 * c;
                o[0] = v.x; o[1] = v.y; o[2] = v.z; o[3] = v.w;
            }
        }
    }

    __syncthreads();

    // ---- store: 897 float4 per block, contiguous -> NT (keep L2 for gathers) ----
    float* __restrict__ oblk = out + (size_t)rbase * OUT_D;
    #pragma unroll
    for (int i = 0; i < 4; ++i) {
        const int c = t + 256 * i;
        if (c < BLK_OUT / 4) {
            const f32x4 v = *reinterpret_cast<const f32x4*>(obuf + 4 * c);
            __builtin_nontemporal_store(v, reinterpret_cast<f32x4*>(oblk) + c);
        }
    }
}

extern "C" void kernel_launch(void* const* d_in, const int* in_sizes, int n_in,
                              void* d_out, int out_size, void* d_ws, size_t ws_size,
                              hipStream_t stream) {
    const int*   item_hist = (const int*)  d_in[0];
    const int*   cate_hist = (const int*)  d_in[1];
    const int*   ctx_ids   = (const int*)  d_in[2];
    const float* price     = (const float*)d_in[3];
    const float* dense_vec = (const float*)d_in[4];
    const float* W_item    = (const float*)d_in[5];
    const float* W_cate    = (const float*)d_in[6];
    const float* W_ctx     = (const float*)d_in[7];
    float* out = (float*)d_out;

    const int B = in_sizes[0] / LH;         // 16384
    const int grid = (B + ROWS - 1) / ROWS;

    const size_t tab_bytes = (size_t)TAB_ELEMS * sizeof(_Float16);  // 12.8 MB
    const size_t ctx_bytes = (size_t)1000 * DX * sizeof(_Float16);  // 64 KB
    if (ws_size >= 2 * tab_bytes + ctx_bytes) {
        _Float16* Hi = (_Float16*)d_ws;
        _Float16* Hc = Hi + TAB_ELEMS;
        _Float16* Hx = Hc + TAB_ELEMS;
        convert_kernel<<<2048, 256, 0, stream>>>(W_item, W_cate, W_ctx, Hi, Hc, Hx);
        featlayer_kernel<true><<<grid, 256, 0, stream>>>(
            item_hist, cate_hist, ctx_ids, price, dense_vec,
            W_item, W_cate, Hi, Hc, Hx, W_ctx, out, B);
    } else {
        featlayer_kernel<false><<<grid, 256, 0, stream>>>(
            item_hist, cate_hist, ctx_ids, price, dense_vec,
            W_item, W_cate, nullptr, nullptr, nullptr, W_ctx, out, B);
    }
}

// Round 10
// 62.697 us; speedup vs baseline: 1.0601x; 1.0601x over previous
//
#include <hip/hip_runtime.h>

// FeatureLayer: out[row] = concat( sum_k W_item[item_hist[row,k]],        (64)
//                                  mean_k W_cate[cate_hist[row,k]],       (64)
//                                  concat_k W_ctx[ctx_ids[row,k]],        (640)
//                                  price[row],                            (1)
//                                  dense_vec[row] )                       (128)
// padding_idx = 0: index 0 contributes zeros. Mean divides by L=50 incl. padding.
//
// R9 model: gather cost = random 128B-line count (R7: bytes/2 at same lines
// -> no gain; R6: lines/2 -> 1.5x). fp16 row = exactly one line = floor.
// This round: revert convert-pass NT loads (R8 regression), make ALL obuf
// LDS writes lane-stride-4B (conflict-free), keep NT only on main-kernel
// streaming loads + full-line output stores.

#define LH 50
#define LC 20
#define DI 64
#define DC 64
#define DX 32
#define DDENSE 128
#define OUT_D 897
#define ROWS 4
#define BLK_OUT (ROWS * OUT_D)   // 3588 floats = 897 float4 exactly
#define NROW_TAB 100000
#define TAB_ELEMS (NROW_TAB * 64)
#define NIT8 7                   // ceil(LH/8)
#define CTX_CHUNKS 8000          // 1000*32/4 f32x4 chunks
#define P_OFF (DI + DC + LC * DX)        // 768: price offset in row
#define D_OFF (DI + DC + LC * DX + 1)    // 769: dense offset in row

typedef float    f32x4 __attribute__((ext_vector_type(4)));
typedef _Float16 f16x4 __attribute__((ext_vector_type(4)));
typedef _Float16 f16x8 __attribute__((ext_vector_type(8)));

// ---------------- pre-pass: fp32 tables + ctx -> fp16 in workspace ----------------
// Plain loads/stores (R6 form: measured ~11 us; NT loads regressed it to ~19).
__global__ __launch_bounds__(256) void convert_kernel(
    const float* __restrict__ Wi, const float* __restrict__ Wc,
    const float* __restrict__ Wx,
    _Float16* __restrict__ Hi, _Float16* __restrict__ Hc,
    _Float16* __restrict__ Hx)
{
    const int gid    = blockIdx.x * 256 + threadIdx.x;
    const int stride = gridDim.x * 256;
    for (int i = gid; i < TAB_ELEMS / 4; i += stride) {
        const f32x4 a = reinterpret_cast<const f32x4*>(Wi)[i];
        const f32x4 b = reinterpret_cast<const f32x4*>(Wc)[i];
        f16x4 ha, hb;
        #pragma unroll
        for (int e = 0; e < 4; ++e) { ha[e] = (_Float16)a[e]; hb[e] = (_Float16)b[e]; }
        reinterpret_cast<f16x4*>(Hi)[i] = ha;
        reinterpret_cast<f16x4*>(Hc)[i] = hb;
    }
    if (gid < CTX_CHUNKS) {
        const f32x4 v = reinterpret_cast<const f32x4*>(Wx)[gid];
        f16x4 h;
        #pragma unroll
        for (int e = 0; e < 4; ++e) h[e] = (_Float16)v[e];
        reinterpret_cast<f16x4*>(Hx)[gid] = h;
    }
}

// ---------------- main kernel ----------------
template <bool HALF>
__global__ __launch_bounds__(256) void featlayer_kernel(
    const int* __restrict__ item_hist,
    const int* __restrict__ cate_hist,
    const int* __restrict__ ctx_ids,
    const float* __restrict__ price,
    const float* __restrict__ dense_vec,
    const float* __restrict__ W_item,
    const float* __restrict__ W_cate,
    const _Float16* __restrict__ H_item,
    const _Float16* __restrict__ H_cate,
    const _Float16* __restrict__ Hx,
    const float* __restrict__ W_ctx,
    float* __restrict__ out,
    int B)
{
    __shared__ __align__(16) float obuf[BLK_OUT];
    __shared__ int ih_s[ROWS * LH];
    __shared__ int ch_s[ROWS * LH];
    __shared__ int cx_s[ROWS * LC];

    const int t     = threadIdx.x;
    const int rbase = blockIdx.x * ROWS;

    // ---- stage indices (read-once: NT; LDS writes lane-stride-4B) ----
    if (t < ROWS * LH) {
        ih_s[t] = __builtin_nontemporal_load(item_hist + (size_t)rbase * LH + t);
        ch_s[t] = __builtin_nontemporal_load(cate_hist + (size_t)rbase * LH + t);
    }
    if (t < ROWS * LC)
        cx_s[t] = __builtin_nontemporal_load(ctx_ids + (size_t)rbase * LC + t);

    // ---- dense: all 256 threads, 2 elems each; obuf writes lane-stride-4B ----
    {
        const int r = t >> 6;          // row 0..3 (one wave per row)
        const int e = t & 63;
        const float* __restrict__ dv = dense_vec + (size_t)(rbase + r) * DDENSE;
        const float d0 = __builtin_nontemporal_load(dv + e);
        const float d1 = __builtin_nontemporal_load(dv + 64 + e);
        obuf[r * OUT_D + D_OFF + e]      = d0;
        obuf[r * OUT_D + D_OFF + 64 + e] = d1;
    }
    if (t < ROWS)
        obuf[t * OUT_D + P_OFF] = __builtin_nontemporal_load(price + rbase + t);

    __syncthreads();

    const int w    = t >> 6;
    const int lane = t & 63;

    if (HALF) {
        // 8 lanes per table row (f16x8 = 16B per lane): one row = one L2 line
        const int sub8 = lane >> 3;   // 0..7: which index within a group of 8
        const int l8   = lane & 7;    // 0..7: which f16x8 of the 64-dim row

        int idxI[NIT8], idxC[NIT8];
        #pragma unroll
        for (int k = 0; k < NIT8; ++k) {
            const int ki = sub8 + 8 * k;
            idxI[k] = (ki < LH) ? ih_s[w * LH + ki] : 0;
            idxC[k] = (ki < LH) ? ch_s[w * LH + ki] : 0;
        }

        float iacc[8] = {0,0,0,0,0,0,0,0};
        float cacc[8] = {0,0,0,0,0,0,0,0};
        #pragma unroll
        for (int k = 0; k < NIT8; ++k) {
            const f16x8 vi = *reinterpret_cast<const f16x8*>(
                H_item + ((size_t)idxI[k] * 64 + l8 * 8));
            const f16x8 vc = *reinterpret_cast<const f16x8*>(
                H_cate + ((size_t)idxC[k] * 64 + l8 * 8));
            const float si = (idxI[k] != 0) ? 1.0f : 0.0f;  // padding_idx
            const float sc = (idxC[k] != 0) ? 1.0f : 0.0f;
            #pragma unroll
            for (int e = 0; e < 8; ++e) {
                iacc[e] += (float)vi[e] * si;
                cacc[e] += (float)vc[e] * sc;
            }
        }

        // combine 8 sub-group partials (lanes l, l+8, ..., l+56)
        #pragma unroll
        for (int e = 0; e < 8; ++e) {
            float a = iacc[e];
            a += __shfl_xor(a, 8, 64);
            a += __shfl_xor(a, 16, 64);
            a += __shfl_xor(a, 32, 64);
            iacc[e] = a;
            float c = cacc[e];
            c += __shfl_xor(c, 8, 64);
            c += __shfl_xor(c, 16, 64);
            c += __shfl_xor(c, 32, 64);
            cacc[e] = c;
        }

        if (sub8 == 0) {   // 8 active lanes; 32B stride = 2-way conflict (free)
            float* oi = obuf + w * OUT_D + l8 * 8;
            float* oc = obuf + w * OUT_D + DI + l8 * 8;
            const float inv = 1.0f / (float)LH;
            #pragma unroll
            for (int e = 0; e < 8; ++e) {
                oi[e] = iacc[e];
                oc[e] = cacc[e] * inv;
            }
        }

        // ---- ctx: 640 floats/row, 10 per lane; lane-stride-4B LDS writes ----
        // Hx is 64 KB, L1/L2-hot: scalar f16 loads are cheap.
        #pragma unroll
        for (int t2 = 0; t2 < 10; ++t2) {
            const int j  = lane + 64 * t2;            // 0..639
            const int id = cx_s[w * LC + (j >> 5)];   // which of the 20 ids
            const float v = (id != 0) ? (float)Hx[id * DX + (j & 31)] : 0.0f;
            obuf[w * OUT_D + DI + DC + j] = v;        // stride 4B: conflict-free
        }
    } else {
        // fp32 fallback: 16 lanes per row (f32x4 per lane)
        const int sub = lane >> 4;
        const int l16 = lane & 15;
        int idxI[13], idxC[13];
        #pragma unroll
        for (int k = 0; k < 13; ++k) {
            const int ki = sub + 4 * k;
            idxI[k] = (ki < LH) ? ih_s[w * LH + ki] : 0;
            idxC[k] = (ki < LH) ? ch_s[w * LH + ki] : 0;
        }
        f32x4 iacc = {0,0,0,0}, cacc = {0,0,0,0};
        #pragma unroll
        for (int k = 0; k < 13; ++k) {
            const f32x4 vi = *reinterpret_cast<const f32x4*>(
                W_item + ((size_t)idxI[k] * DI + l16 * 4));
            const f32x4 vc = *reinterpret_cast<const f32x4*>(
                W_cate + ((size_t)idxC[k] * DC + l16 * 4));
            iacc += vi * ((idxI[k] != 0) ? 1.0f : 0.0f);
            cacc += vc * ((idxC[k] != 0) ? 1.0f : 0.0f);
        }
        #pragma unroll
        for (int e = 0; e < 4; ++e) {
            float a = iacc[e];
            a += __shfl_xor(a, 16, 64); a += __shfl_xor(a, 32, 64);
            iacc[e] = a;
            float c = cacc[e];
            c += __shfl_xor(c, 16, 64); c += __shfl_xor(c, 32, 64);
            cacc[e] = c;
        }
        if (sub == 0) {
            float* oi = obuf + w * OUT_D + l16 * 4;
            float* oc = obuf + w * OUT_D + DI + l16 * 4;
            const float inv = 1.0f / (float)LH;
            #pragma unroll
            for (int e = 0; e < 4; ++e) { oi[e] = iacc[e]; oc[e] = cacc[e] * inv; }
        }
        #pragma unroll
        for (int t2 = 0; t2 < 10; ++t2) {
            const int j  = lane + 64 * t2;
            const int id = cx_s[w * LC + (j >> 5)];
            obuf[w * OUT_D + DI + DC + j] =
                (id != 0) ? W_ctx[id * DX + (j & 31)] : 0.0f;
        }
    }

    __syncthreads();

    // ---- store: 897 float4 per block, contiguous, NT full-line writes ----
    float* __restrict__ oblk = out + (size_t)rbase * OUT_D;
    #pragma unroll
    for (int i = 0; i < 4; ++i) {
        const int c = t + 256 * i;
        if (c < BLK_OUT / 4) {
            const f32x4 v = *reinterpret_cast<const f32x4*>(obuf + 4 * c);
            __builtin_nontemporal_store(v, reinterpret_cast<f32x4*>(oblk) + c);
        }
    }
}

extern "C" void kernel_launch(void* const* d_in, const int* in_sizes, int n_in,
                              void* d_out, int out_size, void* d_ws, size_t ws_size,
                              hipStream_t stream) {
    const int*   item_hist = (const int*)  d_in[0];
    const int*   cate_hist = (const int*)  d_in[1];
    const int*   ctx_ids   = (const int*)  d_in[2];
    const float* price     = (const float*)d_in[3];
    const float* dense_vec = (const float*)d_in[4];
    const float* W_item    = (const float*)d_in[5];
    const float* W_cate    = (const float*)d_in[6];
    const float* W_ctx     = (const float*)d_in[7];
    float* out = (float*)d_out;

    const int B = in_sizes[0] / LH;         // 16384
    const int grid = (B + ROWS - 1) / ROWS;

    const size_t tab_bytes = (size_t)TAB_ELEMS * sizeof(_Float16);  // 12.8 MB
    const size_t ctx_bytes = (size_t)1000 * DX * sizeof(_Float16);  // 64 KB
    if (ws_size >= 2 * tab_bytes + ctx_bytes) {
        _Float16* Hi = (_Float16*)d_ws;
        _Float16* Hc = Hi + TAB_ELEMS;
        _Float16* Hx = Hc + TAB_ELEMS;
        convert_kernel<<<2048, 256, 0, stream>>>(W_item, W_cate, W_ctx, Hi, Hc, Hx);
        featlayer_kernel<true><<<grid, 256, 0, stream>>>(
            item_hist, cate_hist, ctx_ids, price, dense_vec,
            W_item, W_cate, Hi, Hc, Hx, W_ctx, out, B);
    } else {
        featlayer_kernel<false><<<grid, 256, 0, stream>>>(
            item_hist, cate_hist, ctx_ids, price, dense_vec,
            W_item, W_cate, nullptr, nullptr, nullptr, W_ctx, out, B);
    }
}